// Round 1
// baseline (81.206 us; speedup 1.0000x reference)
//
#include <hip/hip_runtime.h>

// out[b,d,t] = 1024*x[b,d,t] - S0[b,d] - (-1)^t * SN[b,d]
//   S0 = sum_t x[t]          (DC bin, dropped by the reference)
//   SN = sum_t (-1)^t x[t]   (Nyquist bin, dropped by the reference)
// Derivation: inverse-rDFT identity; reference keeps bins 1..511 of T=1024.
//
// One 256-thread block per row (8192 rows). Each thread: one float4 load,
// in-register partial sums, 64-lane shuffle reduce, 4-wave LDS combine,
// one float4 store. Memory-bound: 64 MiB total traffic.

#define T_LEN 1024
#define ROWS (64 * 128)

__global__ __launch_bounds__(256) void season_block_46428596469890_kernel(
    const float* __restrict__ x, float* __restrict__ out) {
    const int row = blockIdx.x;
    const int tid = threadIdx.x;

    const float4* xrow = (const float4*)(x + (size_t)row * T_LEN);
    float4* orow       = (float4*)(out + (size_t)row * T_LEN);

    float4 v = xrow[tid];

    // base t index of this float4 is tid*4 (even) -> signs are +,-,+,-
    float s0 = v.x + v.y + v.z + v.w;
    float sN = v.x - v.y + v.z - v.w;

    // 64-lane wave reduction
    #pragma unroll
    for (int off = 32; off > 0; off >>= 1) {
        s0 += __shfl_down(s0, off, 64);
        sN += __shfl_down(sN, off, 64);
    }

    __shared__ float ls0[4];
    __shared__ float lsN[4];
    const int wave = tid >> 6;
    const int lane = tid & 63;
    if (lane == 0) { ls0[wave] = s0; lsN[wave] = sN; }
    __syncthreads();

    const float t0 = ls0[0] + ls0[1] + ls0[2] + ls0[3];
    const float tN = lsN[0] + lsN[1] + lsN[2] + lsN[3];

    float4 o;
    o.x = 1024.0f * v.x - t0 - tN;
    o.y = 1024.0f * v.y - t0 + tN;
    o.z = 1024.0f * v.z - t0 - tN;
    o.w = 1024.0f * v.w - t0 + tN;
    orow[tid] = o;
}

extern "C" void kernel_launch(void* const* d_in, const int* in_sizes, int n_in,
                              void* d_out, int out_size, void* d_ws, size_t ws_size,
                              hipStream_t stream) {
    const float* x = (const float*)d_in[0];
    float* out = (float*)d_out;
    season_block_46428596469890_kernel<<<ROWS, 256, 0, stream>>>(x, out);
}

// Round 3
// 79.768 us; speedup vs baseline: 1.0180x; 1.0180x over previous
//
#include <hip/hip_runtime.h>

// out[b,d,t] = 1024*x[b,d,t] - S0[b,d] - (-1)^t * SN[b,d]
//   S0 = sum_t x[t]          (DC bin, dropped by the reference)
//   SN = sum_t (-1)^t x[t]   (Nyquist bin, dropped by the reference)
// Inverse-rDFT identity; reference keeps bins 1..511 of T=1024, so the
// full 17-GFLOP double-GEMM reduces to a per-row 2-sum + elementwise fixup.
//
// One WAVE (64 lanes) per row: 4x float4 loads/lane, one xor-butterfly
// reduction (no LDS, no __syncthreads), 4x float4 nontemporal stores from
// registers. 8192 rows -> 2048 blocks x 256 threads. Traffic: 64 MiB total.

#define T_LEN 1024
#define ROWS (64 * 128)

typedef float vf4 __attribute__((ext_vector_type(4)));  // clang vector: valid
                                                        // for nontemporal ops

__global__ __launch_bounds__(256) void season_block_46428596469890_kernel(
    const float* __restrict__ x, float* __restrict__ out) {
    const int row  = blockIdx.x * 4 + (threadIdx.x >> 6);  // one wave per row
    const int lane = threadIdx.x & 63;

    const vf4* xrow = (const vf4*)(x + (size_t)row * T_LEN);
    vf4* orow       = (vf4*)(out + (size_t)row * T_LEN);

    vf4 v[4];
    #pragma unroll
    for (int i = 0; i < 4; ++i) v[i] = xrow[lane + 64 * i];

    // float4 base t-index is even everywhere -> signs +,-,+,-
    float s0 = 0.0f, sN = 0.0f;
    #pragma unroll
    for (int i = 0; i < 4; ++i) {
        s0 += (v[i].x + v[i].y) + (v[i].z + v[i].w);
        sN += (v[i].x - v[i].y) + (v[i].z - v[i].w);
    }

    // xor butterfly: all 64 lanes end with the full-row sums
    #pragma unroll
    for (int off = 1; off < 64; off <<= 1) {
        s0 += __shfl_xor(s0, off, 64);
        sN += __shfl_xor(sN, off, 64);
    }

    #pragma unroll
    for (int i = 0; i < 4; ++i) {
        vf4 o;
        o.x = 1024.0f * v[i].x - s0 - sN;
        o.y = 1024.0f * v[i].y - s0 + sN;
        o.z = 1024.0f * v[i].z - s0 - sN;
        o.w = 1024.0f * v[i].w - s0 + sN;
        __builtin_nontemporal_store(o, &orow[lane + 64 * i]);
    }
}

extern "C" void kernel_launch(void* const* d_in, const int* in_sizes, int n_in,
                              void* d_out, int out_size, void* d_ws, size_t ws_size,
                              hipStream_t stream) {
    const float* x = (const float*)d_in[0];
    float* out = (float*)d_out;
    season_block_46428596469890_kernel<<<ROWS / 4, 256, 0, stream>>>(x, out);
}